// Round 3
// baseline (4233.549 us; speedup 1.0000x reference)
//
#include <hip/hip_runtime.h>

typedef short short8 __attribute__((ext_vector_type(8)));
typedef short short4v __attribute__((ext_vector_type(4)));
typedef float f32x4 __attribute__((ext_vector_type(4)));

#define T_SEQ 2048
#define C_DIM 2048
#define H_NUM 16
#define D_HEAD 128
#define B_NUM 4
#define M_ROWS (B_NUM * T_SEQ)   // 8192

__device__ __forceinline__ unsigned short f2bf(float f) {
    union { float f; unsigned u; } v; v.f = f;
    unsigned r = v.u + 0x7FFFu + ((v.u >> 16) & 1u);
    return (unsigned short)(r >> 16);
}
__device__ __forceinline__ float bf2f(unsigned short u) {
    union { unsigned u; float f; } v; v.u = ((unsigned)u) << 16;
    return v.f;
}

// async global->LDS, 16B per lane; lds ptr wave-uniform (HW adds lane*16)
__device__ __forceinline__ void async_ld16(const unsigned short* g, unsigned short* l) {
    __builtin_amdgcn_global_load_lds(
        (const __attribute__((address_space(1))) unsigned int*)g,
        (__attribute__((address_space(3))) unsigned int*)l,
        16, 0, 0);
}

// ---------------- weight cast + transpose: wt[w][n][k] = W_w[k][n] (bf16) ----
__global__ __launch_bounds__(256) void wcast_kernel(const float* __restrict__ W0,
                                                    const float* __restrict__ W1,
                                                    const float* __restrict__ W2,
                                                    const float* __restrict__ W3,
                                                    unsigned short* __restrict__ wt) {
    __shared__ float tile[32][33];
    const float* W = (blockIdx.z == 0) ? W0 : (blockIdx.z == 1) ? W1 : (blockIdx.z == 2) ? W2 : W3;
    unsigned short* out = wt + (size_t)blockIdx.z * C_DIM * C_DIM;
    int tx = threadIdx.x, ty = threadIdx.y;      // block (32, 8)
    int n0 = blockIdx.x * 32, k0 = blockIdx.y * 32;
    #pragma unroll
    for (int j = 0; j < 32; j += 8)
        tile[ty + j][tx] = W[(size_t)(k0 + ty + j) * C_DIM + n0 + tx];
    __syncthreads();
    #pragma unroll
    for (int j = 0; j < 32; j += 8)
        out[(size_t)(n0 + ty + j) * C_DIM + k0 + tx] = f2bf(tile[tx][ty + j]);
}

// ---------------- LayerNorm -> bf16 ----------------------------------------
__global__ __launch_bounds__(256) void ln_kernel(const float* __restrict__ x,
                                                 const float* __restrict__ g,
                                                 const float* __restrict__ bta,
                                                 unsigned short* __restrict__ nx) {
    int row = blockIdx.x;
    int tid = threadIdx.x;
    const float* xr = x + (size_t)row * C_DIM;
    float4 v0 = *(const float4*)(xr + tid * 8);
    float4 v1 = *(const float4*)(xr + tid * 8 + 4);
    float s = v0.x + v0.y + v0.z + v0.w + v1.x + v1.y + v1.z + v1.w;
    float q = v0.x * v0.x + v0.y * v0.y + v0.z * v0.z + v0.w * v0.w +
              v1.x * v1.x + v1.y * v1.y + v1.z * v1.z + v1.w * v1.w;
    #pragma unroll
    for (int m = 32; m; m >>= 1) { s += __shfl_xor(s, m); q += __shfl_xor(q, m); }
    __shared__ float red[2][4];
    int wave = tid >> 6, lane = tid & 63;
    if (lane == 0) { red[0][wave] = s; red[1][wave] = q; }
    __syncthreads();
    s = red[0][0] + red[0][1] + red[0][2] + red[0][3];
    q = red[1][0] + red[1][1] + red[1][2] + red[1][3];
    float mu = s * (1.0f / C_DIM);
    float var = q * (1.0f / C_DIM) - mu * mu;
    float rstd = rsqrtf(var + 1e-5f);
    float4 g0 = *(const float4*)(g + tid * 8);
    float4 g1 = *(const float4*)(g + tid * 8 + 4);
    float4 b0 = *(const float4*)(bta + tid * 8);
    float4 b1 = *(const float4*)(bta + tid * 8 + 4);
    unsigned short o[8];
    o[0] = f2bf((v0.x - mu) * rstd * g0.x + b0.x);
    o[1] = f2bf((v0.y - mu) * rstd * g0.y + b0.y);
    o[2] = f2bf((v0.z - mu) * rstd * g0.z + b0.z);
    o[3] = f2bf((v0.w - mu) * rstd * g0.w + b0.w);
    o[4] = f2bf((v1.x - mu) * rstd * g1.x + b1.x);
    o[5] = f2bf((v1.y - mu) * rstd * g1.y + b1.y);
    o[6] = f2bf((v1.z - mu) * rstd * g1.z + b1.z);
    o[7] = f2bf((v1.w - mu) * rstd * g1.w + b1.w);
    uint4 pk;
    pk.x = (unsigned)o[0] | ((unsigned)o[1] << 16);
    pk.y = (unsigned)o[2] | ((unsigned)o[3] << 16);
    pk.z = (unsigned)o[4] | ((unsigned)o[5] << 16);
    pk.w = (unsigned)o[6] | ((unsigned)o[7] << 16);
    *(uint4*)(nx + (size_t)row * C_DIM + tid * 8) = pk;
}

// ---------------- GEMM core: C[128x128] = A[128xK] * Bt[128xK]^T ------------
__device__ __forceinline__ void gemm_core(const unsigned short* __restrict__ A,
                                          const unsigned short* __restrict__ Bt,
                                          unsigned short* smA, unsigned short* smB,
                                          int rowBase, int colBase, f32x4 acc[4][4]) {
    const int tid = threadIdx.x;
    const int lane = tid & 63, wave = tid >> 6;
    const int quad = lane >> 4, lo = lane & 15;
    const int wrow = (wave >> 1) * 64, wcol = (wave & 1) * 64;
    for (int kt = 0; kt < C_DIM; kt += 32) {
        #pragma unroll
        for (int it = 0; it < 2; it++) {
            int ubase = it * 256 + wave * 64;      // wave-uniform LDS chunk base
            int u = ubase + lane;
            int r = u >> 2, c = u & 3;
            async_ld16(A + (size_t)(rowBase + r) * C_DIM + kt + c * 8, smA + (size_t)ubase * 8);
            async_ld16(Bt + (size_t)(colBase + r) * C_DIM + kt + c * 8, smB + (size_t)ubase * 8);
        }
        __syncthreads();
        short8 af[4], bf[4];
        #pragma unroll
        for (int mi = 0; mi < 4; mi++)
            af[mi] = *(const short8*)(smA + (wrow + mi * 16 + lo) * 32 + quad * 8);
        #pragma unroll
        for (int ni = 0; ni < 4; ni++)
            bf[ni] = *(const short8*)(smB + (wcol + ni * 16 + lo) * 32 + quad * 8);
        #pragma unroll
        for (int mi = 0; mi < 4; mi++)
            #pragma unroll
            for (int ni = 0; ni < 4; ni++)
                acc[mi][ni] = __builtin_amdgcn_mfma_f32_16x16x32_bf16(af[mi], bf[ni], acc[mi][ni], 0, 0, 0);
        __syncthreads();
    }
}

// ---------------- fused QKV GEMM (N = 6144) ---------------------------------
__global__ __launch_bounds__(256) void gemm_qkv(const unsigned short* __restrict__ A,
                                                const unsigned short* __restrict__ Bt,
                                                const float* __restrict__ bq,
                                                const float* __restrict__ bk,
                                                const float* __restrict__ bv,
                                                unsigned short* __restrict__ qb,
                                                unsigned short* __restrict__ kb,
                                                unsigned short* __restrict__ vtb) {
    __shared__ uint4 smAq[512];
    __shared__ uint4 smBq[512];
    f32x4 acc[4][4] = {};
    int rowBase = blockIdx.y * 128;
    int colBase = blockIdx.x * 128;
    gemm_core(A, Bt, (unsigned short*)smAq, (unsigned short*)smBq, rowBase, colBase, acc);

    const int lane = threadIdx.x & 63, wave = threadIdx.x >> 6;
    const int quad = lane >> 4, lo = lane & 15;
    const int wrow = (wave >> 1) * 64, wcol = (wave & 1) * 64;
    const int which = colBase >> 11;
    const float* bias = (which == 0) ? bq : (which == 1) ? bk : bv;
    #pragma unroll
    for (int mi = 0; mi < 4; mi++)
        #pragma unroll
        for (int ni = 0; ni < 4; ni++) {
            int n = colBase + wcol + ni * 16 + lo;
            int c = n & (C_DIM - 1), h = c >> 7, d = c & 127;
            float bsv = bias[c];
            #pragma unroll
            for (int r = 0; r < 4; r++) {
                int m = rowBase + wrow + mi * 16 + quad * 4 + r;
                int bb = m >> 11, t = m & (T_SEQ - 1);
                unsigned short u = f2bf(acc[mi][ni][r] + bsv);
                if (which == 2)
                    vtb[(size_t)((bb * H_NUM + h) * D_HEAD + d) * T_SEQ + t] = u;
                else if (which == 1)
                    kb[(size_t)((bb * H_NUM + h) * T_SEQ + t) * D_HEAD + d] = u;
                else
                    qb[(size_t)((bb * H_NUM + h) * T_SEQ + t) * D_HEAD + d] = u;
            }
        }
}

// ---------------- output GEMM + bias + residual -----------------------------
__global__ __launch_bounds__(256) void gemm_out(const unsigned short* __restrict__ A,
                                                const unsigned short* __restrict__ Bt,
                                                const float* __restrict__ bo,
                                                const float* __restrict__ x,
                                                float* __restrict__ out) {
    __shared__ uint4 smAq[512];
    __shared__ uint4 smBq[512];
    f32x4 acc[4][4] = {};
    int rowBase = blockIdx.y * 128;
    int colBase = blockIdx.x * 128;
    gemm_core(A, Bt, (unsigned short*)smAq, (unsigned short*)smBq, rowBase, colBase, acc);

    const int lane = threadIdx.x & 63, wave = threadIdx.x >> 6;
    const int quad = lane >> 4, lo = lane & 15;
    const int wrow = (wave >> 1) * 64, wcol = (wave & 1) * 64;
    #pragma unroll
    for (int mi = 0; mi < 4; mi++)
        #pragma unroll
        for (int ni = 0; ni < 4; ni++) {
            int n = colBase + wcol + ni * 16 + lo;
            float bsv = bo[n];
            #pragma unroll
            for (int r = 0; r < 4; r++) {
                int m = rowBase + wrow + mi * 16 + quad * 4 + r;
                size_t idx = (size_t)m * C_DIM + n;
                out[idx] = x[idx] + acc[mi][ni][r] + bsv;
            }
        }
}

// ---------------- RoPE (in-place, bf16) -------------------------------------
// Q is pre-scaled by log2(e)/sqrt(D) so attention works in exp2 domain.
__global__ __launch_bounds__(256) void rope_kernel(unsigned short* __restrict__ qb,
                                                   unsigned short* __restrict__ kb) {
    const bool isk = (blockIdx.y != 0);
    unsigned short* p = isk ? kb : qb;
    const float osc = isk ? 1.0f : 0.12751736f;    // log2(e)/sqrt(128)
    int pidx = blockIdx.x * 256 + threadIdx.x;     // 0 .. B*H*T*64-1
    int dd = pidx & 63;
    int bht = pidx >> 6;
    int t = bht & (T_SEQ - 1);
    unsigned short* base = p + (size_t)bht * D_HEAD;
    float x0 = bf2f(base[dd]);
    float x1 = bf2f(base[dd + 64]);
    float inv = exp2f((float)dd * (-13.287712379549449f / 64.0f));  // 10000^(-dd/64)
    float ang = (float)t * inv;
    float sn = __sinf(ang), cs = __cosf(ang);
    base[dd]      = f2bf((x0 * cs - x1 * sn) * osc);
    base[dd + 64] = f2bf((x1 * cs + x0 * sn) * osc);
}

// ---------------- causal flash attention (v3) --------------------------------
// Block = 4 waves = 128 q-rows of one head. Pair (tile, 15-tile) => 34 k-tile
// iterations constant. K/V staged in LDS (double-buffered, global_load_lds,
// manual vmcnt(8) + raw s_barrier so prefetch stays in flight). S^T orientation:
// softmax = 2 shfls; P^T feeds PV straight from registers (zero-padded K=32).

// stage one 64-key tile: K[64][128] (chunk-swizzled) + V^T[128][64] (unit-swizzled)
__device__ __forceinline__ void attn_stage(const unsigned short* __restrict__ kh,
                                           const unsigned short* __restrict__ vh,
                                           int kt, unsigned short* Kd, unsigned short* Vd,
                                           int w, int lane) {
    const int l4 = lane >> 4, c16 = lane & 15;
    const int l8 = lane >> 3, c8 = lane & 7;
    #pragma unroll
    for (int j = 0; j < 4; j++) {
        int row = w * 16 + j * 4 + l4;
        int cl = c16 ^ (row & 15);                 // LDS slot (row,cs) holds chunk cs^row15
        async_ld16(kh + (size_t)(kt * 64 + row) * D_HEAD + cl * 8,
                   Kd + (w * 16 + j * 4) * D_HEAD);
    }
    #pragma unroll
    for (int j = 0; j < 4; j++) {
        int row = (w * 4 + j) * 8 + l8;
        int gu = (2 * c8) ^ (row & 14);            // 8B-unit swizzle, even mask keeps pairs
        async_ld16(vh + (size_t)row * T_SEQ + kt * 64 + gu * 4,
                   Vd + (w * 4 + j) * 512);
    }
}

__device__ __forceinline__ void softmax_group(const f32x4 s[4], int kt, int a, int tq, int quad,
                                              float& m_i, float& l_i, float& alpha, short8 pp[4]) {
    float sv[16];
    const bool msk = (kt == a);
    float mx = -1e30f;
    #pragma unroll
    for (int kg = 0; kg < 4; kg++)
        #pragma unroll
        for (int r = 0; r < 4; r++) {
            float s_ = s[kg][r];
            if (msk) {
                int key = kt * 64 + kg * 16 + quad * 4 + r;
                s_ = (key <= tq) ? s_ : -1e30f;
            }
            sv[kg * 4 + r] = s_;
            mx = fmaxf(mx, s_);
        }
    mx = fmaxf(mx, __shfl_xor(mx, 16));
    mx = fmaxf(mx, __shfl_xor(mx, 32));
    float mnew = fmaxf(m_i, mx);
    alpha = __builtin_amdgcn_exp2f(m_i - mnew);
    float sm = 0.f;
    unsigned pk[8];
    #pragma unroll
    for (int i = 0; i < 16; i++) {
        float p = __builtin_amdgcn_exp2f(sv[i] - mnew);
        sm += p;
        union { float f; unsigned u; } c; c.f = p;
        if ((i & 1) == 0) pk[i >> 1] = c.u >> 16;            // truncated bf16, low half
        else pk[i >> 1] |= (c.u & 0xFFFF0000u);              // high half
    }
    sm += __shfl_xor(sm, 16);
    sm += __shfl_xor(sm, 32);
    l_i = l_i * alpha + sm;
    m_i = mnew;
    #pragma unroll
    for (int kg = 0; kg < 4; kg++) {
        union { short8 s8; unsigned u[4]; } pu;
        pu.u[0] = pk[kg * 2]; pu.u[1] = pk[kg * 2 + 1]; pu.u[2] = 0; pu.u[3] = 0;
        pp[kg] = pu.s8;
    }
}

__device__ __forceinline__ void attn_tile128(const unsigned short* __restrict__ qh,
                                             const unsigned short* __restrict__ kh,
                                             const unsigned short* __restrict__ vh,
                                             unsigned short* __restrict__ attn_out,
                                             int tile, int b, int h, int w, int quad,
                                             int lo, int lane,
                                             unsigned short* Kb, unsigned short* Vb) {
    const int Rb = tile * 128;
    const int nkt = 2 * tile + 2;
    const int G0 = Rb + 16 * w;                  // wave's two 16-row groups (balanced)
    const int G1 = Rb + 16 * (7 - w);
    const int a0 = G0 >> 6, a1 = G1 >> 6;        // last needed k-tile per group
    const int tq0 = G0 + lo, tq1 = G1 + lo;

    short8 qf0[4], qf1[4];
    #pragma unroll
    for (int ks = 0; ks < 4; ks++) {
        qf0[ks] = *(const short8*)(qh + (size_t)(G0 + lo) * D_HEAD + ks * 32 + quad * 8);
        qf1[ks] = *(const short8*)(qh + (size_t)(G1 + lo) * D_HEAD + ks * 32 + quad * 8);
    }
    float m0 = -1e30f, m1 = -1e30f, l0 = 0.f, l1 = 0.f;
    f32x4 o0[8], o1[8];
    #pragma unroll
    for (int dt = 0; dt < 8; dt++) { o0[dt] = (f32x4){0.f,0.f,0.f,0.f}; o1[dt] = (f32x4){0.f,0.f,0.f,0.f}; }

    attn_stage(kh, vh, 0, Kb, Vb, w, lane);
    for (int kt = 0; kt < nkt; kt++) {
        const int cur = kt & 1;
        if (kt + 1 < nkt) {
            attn_stage(kh, vh, kt + 1, Kb + (cur ^ 1) * (64 * 128), Vb + (cur ^ 1) * (128 * 64), w, lane);
            __builtin_amdgcn_s_waitcnt(0x3F78);   // vmcnt(8): this tile's 8 loads done
        } else {
            __builtin_amdgcn_s_waitcnt(0x3F70);   // vmcnt(0)
        }
        __asm__ volatile("" ::: "memory");
        __builtin_amdgcn_s_barrier();
        __asm__ volatile("" ::: "memory");
        const unsigned short* Kc = Kb + cur * (64 * 128);
        const unsigned short* Vc = Vb + cur * (128 * 64);
        const bool act0 = (kt <= a0), act1 = (kt <= a1);

        // QK: S^T[key][qrow] = K . Q^T
        f32x4 s0[4], s1[4];
        #pragma unroll
        for (int kg = 0; kg < 4; kg++) { s0[kg] = (f32x4){0.f,0.f,0.f,0.f}; s1[kg] = (f32x4){0.f,0.f,0.f,0.f}; }
        #pragma unroll
        for (int kg = 0; kg < 4; kg++) {
            short8 kf[4];
            #pragma unroll
            for (int ks = 0; ks < 4; ks++) {
                int ch = (ks * 4 + quad) ^ lo;   // row&15 == lo
                kf[ks] = *(const short8*)(Kc + (kg * 16 + lo) * D_HEAD + ch * 8);
            }
            if (act0) {
                #pragma unroll
                for (int ks = 0; ks < 4; ks++)
                    s0[kg] = __builtin_amdgcn_mfma_f32_16x16x32_bf16(kf[ks], qf0[ks], s0[kg], 0, 0, 0);
            }
            if (act1) {
                #pragma unroll
                for (int ks = 0; ks < 4; ks++)
                    s1[kg] = __builtin_amdgcn_mfma_f32_16x16x32_bf16(kf[ks], qf1[ks], s1[kg], 0, 0, 0);
            }
        }

        short8 pp0[4], pp1[4];
        float al0 = 1.f, al1 = 1.f;
        if (act0) softmax_group(s0, kt, a0, tq0, quad, m0, l0, al0, pp0);
        if (act1) softmax_group(s1, kt, a1, tq1, quad, m1, l1, al1, pp1);
        if (act0) {
            #pragma unroll
            for (int dt = 0; dt < 8; dt++)
                #pragma unroll
                for (int r = 0; r < 4; r++) o0[dt][r] *= al0;
        }
        if (act1) {
            #pragma unroll
            for (int dt = 0; dt < 8; dt++)
                #pragma unroll
                for (int r = 0; r < 4; r++) o1[dt][r] *= al1;
        }

        // PV: O^T[d][qrow] += V^T . P^T  (K=32 MFMA, upper 4 k-slots zeroed)
        #pragma unroll
        for (int dt = 0; dt < 8; dt++) {
            #pragma unroll
            for (int kg = 0; kg < 4; kg++) {
                int un = (kg * 4 + quad) ^ (lo & 14);       // vrow&14 == lo&14
                short4v vv = *(const short4v*)(Vc + (dt * 16 + lo) * 64 + un * 4);
                short8 vf = {vv[0], vv[1], vv[2], vv[3], 0, 0, 0, 0};
                if (act0) o0[dt] = __builtin_amdgcn_mfma_f32_16x16x32_bf16(vf, pp0[kg], o0[dt], 0, 0, 0);
                if (act1) o1[dt] = __builtin_amdgcn_mfma_f32_16x16x32_bf16(vf, pp1[kg], o1[dt], 0, 0, 0);
            }
        }
        __asm__ volatile("" ::: "memory");
        __builtin_amdgcn_s_barrier();
        __asm__ volatile("" ::: "memory");
    }

    // epilogue: O^T C-layout lane(quad,lo): d = dt*16+quad*4+r, qrow = G+lo
    float inv0 = 1.f / l0, inv1 = 1.f / l1;
    size_t base0 = ((size_t)b * T_SEQ + G0 + lo) * C_DIM + h * D_HEAD + quad * 4;
    size_t base1 = ((size_t)b * T_SEQ + G1 + lo) * C_DIM + h * D_HEAD + quad * 4;
    #pragma unroll
    for (int dt = 0; dt < 8; dt++) {
        uint2 u0, u1;
        u0.x = (unsigned)f2bf(o0[dt][0] * inv0) | ((unsigned)f2bf(o0[dt][1] * inv0) << 16);
        u0.y = (unsigned)f2bf(o0[dt][2] * inv0) | ((unsigned)f2bf(o0[dt][3] * inv0) << 16);
        u1.x = (unsigned)f2bf(o1[dt][0] * inv1) | ((unsigned)f2bf(o1[dt][1] * inv1) << 16);
        u1.y = (unsigned)f2bf(o1[dt][2] * inv1) | ((unsigned)f2bf(o1[dt][3] * inv1) << 16);
        *(uint2*)(attn_out + base0 + dt * 16) = u0;
        *(uint2*)(attn_out + base1 + dt * 16) = u1;
    }
}

__global__ __launch_bounds__(256, 2) void attn_kernel(const unsigned short* __restrict__ q,
                                                      const unsigned short* __restrict__ k,
                                                      const unsigned short* __restrict__ vt,
                                                      unsigned short* __restrict__ attn_out) {
    __shared__ unsigned short Kb[2 * 64 * 128];   // 32 KB
    __shared__ unsigned short Vb[2 * 128 * 64];   // 32 KB
    const int lane = threadIdx.x & 63;
    const int w = threadIdx.x >> 6;
    const int quad = lane >> 4, lo = lane & 15;
    const int bid = blockIdx.x;                   // 512 blocks = 2/CU
    const int head_lin = (bid & 7) * 8 + (bid >> 6);   // XCD-clustered heads
    const int pr = (bid >> 3) & 7;                // pair index 0..7
    const int b = head_lin >> 4, h = head_lin & 15;
    const unsigned short* qh = q + (size_t)head_lin * T_SEQ * D_HEAD;
    const unsigned short* kh = k + (size_t)head_lin * T_SEQ * D_HEAD;
    const unsigned short* vh = vt + (size_t)head_lin * D_HEAD * T_SEQ;

    attn_tile128(qh, kh, vh, attn_out, pr,      b, h, w, quad, lo, lane, Kb, Vb);  // light
    attn_tile128(qh, kh, vh, attn_out, 15 - pr, b, h, w, quad, lo, lane, Kb, Vb);  // heavy
}

// ---------------- launch -----------------------------------------------------
extern "C" void kernel_launch(void* const* d_in, const int* in_sizes, int n_in,
                              void* d_out, int out_size, void* d_ws, size_t ws_size,
                              hipStream_t stream) {
    const float* x    = (const float*)d_in[0];
    const float* ln_g = (const float*)d_in[1];
    const float* ln_b = (const float*)d_in[2];
    const float* Wq   = (const float*)d_in[3];
    const float* bq   = (const float*)d_in[4];
    const float* Wk   = (const float*)d_in[5];
    const float* bk   = (const float*)d_in[6];
    const float* Wv   = (const float*)d_in[7];
    const float* bv   = (const float*)d_in[8];
    const float* Wo   = (const float*)d_in[9];
    const float* bo   = (const float*)d_in[10];
    float* out = (float*)d_out;

    char* ws = (char*)d_ws;
    const size_t SZ = (size_t)M_ROWS * C_DIM * 2;        // 33,554,432 bytes
    unsigned short* nx  = (unsigned short*)(ws);
    unsigned short* wt  = (unsigned short*)(ws + SZ);    // 4 x 2048 x 2048 bf16
    unsigned short* qb  = (unsigned short*)(ws + 2 * SZ);
    unsigned short* kb  = (unsigned short*)(ws + 3 * SZ);
    unsigned short* vtb = (unsigned short*)(ws + 4 * SZ);
    unsigned short* at  = (unsigned short*)(ws + 5 * SZ);

    wcast_kernel<<<dim3(64, 64, 4), dim3(32, 8), 0, stream>>>(Wq, Wk, Wv, Wo, wt);
    ln_kernel<<<M_ROWS, 256, 0, stream>>>(x, ln_g, ln_b, nx);
    gemm_qkv<<<dim3(48, 64), 256, 0, stream>>>(nx, wt, bq, bk, bv, qb, kb, vtb);
    rope_kernel<<<dim3((B_NUM * H_NUM * T_SEQ * 64) / 256, 2), 256, 0, stream>>>(qb, kb);
    attn_kernel<<<512, 256, 0, stream>>>(qb, kb, vtb, at);
    gemm_out<<<dim3(16, 64), 256, 0, stream>>>(at, wt + (size_t)3 * C_DIM * C_DIM, bo, x, out);
}

// Round 4
// 722.764 us; speedup vs baseline: 5.8574x; 5.8574x over previous
//
#include <hip/hip_runtime.h>

typedef short short8 __attribute__((ext_vector_type(8)));
typedef short short4v __attribute__((ext_vector_type(4)));
typedef float f32x4 __attribute__((ext_vector_type(4)));

#define T_SEQ 2048
#define C_DIM 2048
#define H_NUM 16
#define D_HEAD 128
#define B_NUM 4
#define M_ROWS (B_NUM * T_SEQ)   // 8192

__device__ __forceinline__ unsigned short f2bf(float f) {
    union { float f; unsigned u; } v; v.f = f;
    unsigned r = v.u + 0x7FFFu + ((v.u >> 16) & 1u);
    return (unsigned short)(r >> 16);
}
__device__ __forceinline__ float bf2f(unsigned short u) {
    union { unsigned u; float f; } v; v.u = ((unsigned)u) << 16;
    return v.f;
}

// async global->LDS, 16B per lane; lds ptr wave-uniform (HW adds lane*16)
__device__ __forceinline__ void async_ld16(const unsigned short* g, unsigned short* l) {
    __builtin_amdgcn_global_load_lds(
        (const __attribute__((address_space(1))) unsigned int*)g,
        (__attribute__((address_space(3))) unsigned int*)l,
        16, 0, 0);
}

// PV matmul: K=16 keys per group. Prefer native 16x16x16 (half issue cost,
// half A/B regs); fall back to verified zero-padded K=32 form.
__device__ __forceinline__ f32x4 pv_mfma(short4v v, short4v p, f32x4 c) {
#if __has_builtin(__builtin_amdgcn_mfma_f32_16x16x16bf16_1k)
    return __builtin_amdgcn_mfma_f32_16x16x16bf16_1k(v, p, c, 0, 0, 0);
#else
    short8 vf = {v[0], v[1], v[2], v[3], 0, 0, 0, 0};
    short8 pf = {p[0], p[1], p[2], p[3], 0, 0, 0, 0};
    return __builtin_amdgcn_mfma_f32_16x16x32_bf16(vf, pf, c, 0, 0, 0);
#endif
}

// ---------------- weight cast + transpose: wt[w][n][k] = W_w[k][n] (bf16) ----
__global__ __launch_bounds__(256) void wcast_kernel(const float* __restrict__ W0,
                                                    const float* __restrict__ W1,
                                                    const float* __restrict__ W2,
                                                    const float* __restrict__ W3,
                                                    unsigned short* __restrict__ wt) {
    __shared__ float tile[32][33];
    const float* W = (blockIdx.z == 0) ? W0 : (blockIdx.z == 1) ? W1 : (blockIdx.z == 2) ? W2 : W3;
    unsigned short* out = wt + (size_t)blockIdx.z * C_DIM * C_DIM;
    int tx = threadIdx.x, ty = threadIdx.y;      // block (32, 8)
    int n0 = blockIdx.x * 32, k0 = blockIdx.y * 32;
    #pragma unroll
    for (int j = 0; j < 32; j += 8)
        tile[ty + j][tx] = W[(size_t)(k0 + ty + j) * C_DIM + n0 + tx];
    __syncthreads();
    #pragma unroll
    for (int j = 0; j < 32; j += 8)
        out[(size_t)(n0 + ty + j) * C_DIM + k0 + tx] = f2bf(tile[tx][ty + j]);
}

// ---------------- LayerNorm -> bf16 ----------------------------------------
__global__ __launch_bounds__(256) void ln_kernel(const float* __restrict__ x,
                                                 const float* __restrict__ g,
                                                 const float* __restrict__ bta,
                                                 unsigned short* __restrict__ nx) {
    int row = blockIdx.x;
    int tid = threadIdx.x;
    const float* xr = x + (size_t)row * C_DIM;
    float4 v0 = *(const float4*)(xr + tid * 8);
    float4 v1 = *(const float4*)(xr + tid * 8 + 4);
    float s = v0.x + v0.y + v0.z + v0.w + v1.x + v1.y + v1.z + v1.w;
    float q = v0.x * v0.x + v0.y * v0.y + v0.z * v0.z + v0.w * v0.w +
              v1.x * v1.x + v1.y * v1.y + v1.z * v1.z + v1.w * v1.w;
    #pragma unroll
    for (int m = 32; m; m >>= 1) { s += __shfl_xor(s, m); q += __shfl_xor(q, m); }
    __shared__ float red[2][4];
    int wave = tid >> 6, lane = tid & 63;
    if (lane == 0) { red[0][wave] = s; red[1][wave] = q; }
    __syncthreads();
    s = red[0][0] + red[0][1] + red[0][2] + red[0][3];
    q = red[1][0] + red[1][1] + red[1][2] + red[1][3];
    float mu = s * (1.0f / C_DIM);
    float var = q * (1.0f / C_DIM) - mu * mu;
    float rstd = rsqrtf(var + 1e-5f);
    float4 g0 = *(const float4*)(g + tid * 8);
    float4 g1 = *(const float4*)(g + tid * 8 + 4);
    float4 b0 = *(const float4*)(bta + tid * 8);
    float4 b1 = *(const float4*)(bta + tid * 8 + 4);
    unsigned short o[8];
    o[0] = f2bf((v0.x - mu) * rstd * g0.x + b0.x);
    o[1] = f2bf((v0.y - mu) * rstd * g0.y + b0.y);
    o[2] = f2bf((v0.z - mu) * rstd * g0.z + b0.z);
    o[3] = f2bf((v0.w - mu) * rstd * g0.w + b0.w);
    o[4] = f2bf((v1.x - mu) * rstd * g1.x + b1.x);
    o[5] = f2bf((v1.y - mu) * rstd * g1.y + b1.y);
    o[6] = f2bf((v1.z - mu) * rstd * g1.z + b1.z);
    o[7] = f2bf((v1.w - mu) * rstd * g1.w + b1.w);
    uint4 pk;
    pk.x = (unsigned)o[0] | ((unsigned)o[1] << 16);
    pk.y = (unsigned)o[2] | ((unsigned)o[3] << 16);
    pk.z = (unsigned)o[4] | ((unsigned)o[5] << 16);
    pk.w = (unsigned)o[6] | ((unsigned)o[7] << 16);
    *(uint4*)(nx + (size_t)row * C_DIM + tid * 8) = pk;
}

// ---------------- GEMM core: C[128x128] = A[128xK] * Bt[128xK]^T ------------
__device__ __forceinline__ void gemm_core(const unsigned short* __restrict__ A,
                                          const unsigned short* __restrict__ Bt,
                                          unsigned short* smA, unsigned short* smB,
                                          int rowBase, int colBase, f32x4 acc[4][4]) {
    const int tid = threadIdx.x;
    const int lane = tid & 63, wave = tid >> 6;
    const int quad = lane >> 4, lo = lane & 15;
    const int wrow = (wave >> 1) * 64, wcol = (wave & 1) * 64;
    for (int kt = 0; kt < C_DIM; kt += 32) {
        #pragma unroll
        for (int it = 0; it < 2; it++) {
            int ubase = it * 256 + wave * 64;      // wave-uniform LDS chunk base
            int u = ubase + lane;
            int r = u >> 2, c = u & 3;
            async_ld16(A + (size_t)(rowBase + r) * C_DIM + kt + c * 8, smA + (size_t)ubase * 8);
            async_ld16(Bt + (size_t)(colBase + r) * C_DIM + kt + c * 8, smB + (size_t)ubase * 8);
        }
        __syncthreads();
        short8 af[4], bf[4];
        #pragma unroll
        for (int mi = 0; mi < 4; mi++)
            af[mi] = *(const short8*)(smA + (wrow + mi * 16 + lo) * 32 + quad * 8);
        #pragma unroll
        for (int ni = 0; ni < 4; ni++)
            bf[ni] = *(const short8*)(smB + (wcol + ni * 16 + lo) * 32 + quad * 8);
        #pragma unroll
        for (int mi = 0; mi < 4; mi++)
            #pragma unroll
            for (int ni = 0; ni < 4; ni++)
                acc[mi][ni] = __builtin_amdgcn_mfma_f32_16x16x32_bf16(af[mi], bf[ni], acc[mi][ni], 0, 0, 0);
        __syncthreads();
    }
}

// ---------------- fused QKV GEMM (N = 6144) ---------------------------------
__global__ __launch_bounds__(256) void gemm_qkv(const unsigned short* __restrict__ A,
                                                const unsigned short* __restrict__ Bt,
                                                const float* __restrict__ bq,
                                                const float* __restrict__ bk,
                                                const float* __restrict__ bv,
                                                unsigned short* __restrict__ qb,
                                                unsigned short* __restrict__ kb,
                                                unsigned short* __restrict__ vtb) {
    __shared__ uint4 smAq[512];
    __shared__ uint4 smBq[512];
    f32x4 acc[4][4] = {};
    int rowBase = blockIdx.y * 128;
    int colBase = blockIdx.x * 128;
    gemm_core(A, Bt, (unsigned short*)smAq, (unsigned short*)smBq, rowBase, colBase, acc);

    const int lane = threadIdx.x & 63, wave = threadIdx.x >> 6;
    const int quad = lane >> 4, lo = lane & 15;
    const int wrow = (wave >> 1) * 64, wcol = (wave & 1) * 64;
    const int which = colBase >> 11;
    const float* bias = (which == 0) ? bq : (which == 1) ? bk : bv;
    #pragma unroll
    for (int mi = 0; mi < 4; mi++)
        #pragma unroll
        for (int ni = 0; ni < 4; ni++) {
            int n = colBase + wcol + ni * 16 + lo;
            int c = n & (C_DIM - 1), h = c >> 7, d = c & 127;
            float bsv = bias[c];
            #pragma unroll
            for (int r = 0; r < 4; r++) {
                int m = rowBase + wrow + mi * 16 + quad * 4 + r;
                int bb = m >> 11, t = m & (T_SEQ - 1);
                unsigned short u = f2bf(acc[mi][ni][r] + bsv);
                if (which == 2)
                    vtb[(size_t)((bb * H_NUM + h) * D_HEAD + d) * T_SEQ + t] = u;
                else if (which == 1)
                    kb[(size_t)((bb * H_NUM + h) * T_SEQ + t) * D_HEAD + d] = u;
                else
                    qb[(size_t)((bb * H_NUM + h) * T_SEQ + t) * D_HEAD + d] = u;
            }
        }
}

// ---------------- output GEMM + bias + residual -----------------------------
__global__ __launch_bounds__(256) void gemm_out(const unsigned short* __restrict__ A,
                                                const unsigned short* __restrict__ Bt,
                                                const float* __restrict__ bo,
                                                const float* __restrict__ x,
                                                float* __restrict__ out) {
    __shared__ uint4 smAq[512];
    __shared__ uint4 smBq[512];
    f32x4 acc[4][4] = {};
    int rowBase = blockIdx.y * 128;
    int colBase = blockIdx.x * 128;
    gemm_core(A, Bt, (unsigned short*)smAq, (unsigned short*)smBq, rowBase, colBase, acc);

    const int lane = threadIdx.x & 63, wave = threadIdx.x >> 6;
    const int quad = lane >> 4, lo = lane & 15;
    const int wrow = (wave >> 1) * 64, wcol = (wave & 1) * 64;
    #pragma unroll
    for (int mi = 0; mi < 4; mi++)
        #pragma unroll
        for (int ni = 0; ni < 4; ni++) {
            int n = colBase + wcol + ni * 16 + lo;
            float bsv = bo[n];
            #pragma unroll
            for (int r = 0; r < 4; r++) {
                int m = rowBase + wrow + mi * 16 + quad * 4 + r;
                size_t idx = (size_t)m * C_DIM + n;
                out[idx] = x[idx] + acc[mi][ni][r] + bsv;
            }
        }
}

// ---------------- RoPE (in-place, bf16) -------------------------------------
// Q is pre-scaled by log2(e)/sqrt(D) so attention works in exp2 domain.
__global__ __launch_bounds__(256) void rope_kernel(unsigned short* __restrict__ qb,
                                                   unsigned short* __restrict__ kb) {
    const bool isk = (blockIdx.y != 0);
    unsigned short* p = isk ? kb : qb;
    const float osc = isk ? 1.0f : 0.12751736f;    // log2(e)/sqrt(128)
    int pidx = blockIdx.x * 256 + threadIdx.x;     // 0 .. B*H*T*64-1
    int dd = pidx & 63;
    int bht = pidx >> 6;
    int t = bht & (T_SEQ - 1);
    unsigned short* base = p + (size_t)bht * D_HEAD;
    float x0 = bf2f(base[dd]);
    float x1 = bf2f(base[dd + 64]);
    float inv = exp2f((float)dd * (-13.287712379549449f / 64.0f));  // 10000^(-dd/64)
    float ang = (float)t * inv;
    float sn = __sinf(ang), cs = __cosf(ang);
    base[dd]      = f2bf((x0 * cs - x1 * sn) * osc);
    base[dd + 64] = f2bf((x1 * cs + x0 * sn) * osc);
}

// ---------------- causal flash attention (v4) --------------------------------
// Block = 8 waves (512 thr) = 128 q-rows of one head; ONE 16-row group per wave
// (v3's two-group scheme spilled: 9.4 GB scratch writes). K/V double-buffered
// in LDS via global_load_lds, manual vmcnt(4) + raw s_barrier. S^T orientation:
// 2-shfl softmax, P^T feeds PV straight from registers (K=16 MFMA).
// Pair (tile, 15-tile) per block => constant 34 k-tile iterations; 512 blocks
// = 2/CU co-resident; bid=pr*64+head clusters a head's 8 blocks on one XCD.

// stage one 64-key tile: K[64][128] (chunk-swizzled) + V^T[128][64] (unit-swizzled)
// 8 waves x 4 async ops; swizzles verified in r3 (SQ_LDS_BANK_CONFLICT = 0).
__device__ __forceinline__ void attn_stage(const unsigned short* __restrict__ kh,
                                           const unsigned short* __restrict__ vh,
                                           int kt, unsigned short* Kd, unsigned short* Vd,
                                           int w, int lane) {
    const int l4 = lane >> 4, c16 = lane & 15;
    const int l8 = lane >> 3, c8 = lane & 7;
    #pragma unroll
    for (int j = 0; j < 2; j++) {
        int R = w * 8 + j * 4;                     // K rows R..R+3
        int row = R + l4;
        int cl = c16 ^ (row & 15);                 // LDS slot (row,cs) holds chunk cs^row15
        async_ld16(kh + (size_t)(kt * 64 + row) * D_HEAD + cl * 8, Kd + R * D_HEAD);
    }
    #pragma unroll
    for (int j = 0; j < 2; j++) {
        int o8 = w * 2 + j;                        // V 8-row chunk 0..15
        int row = o8 * 8 + l8;
        int gu = (2 * c8) ^ (row & 14);            // 8B-unit swizzle, even mask keeps pairs
        async_ld16(vh + (size_t)row * T_SEQ + kt * 64 + gu * 4, Vd + o8 * 512);
    }
}

__device__ __forceinline__ void attn_tile128(const unsigned short* __restrict__ qh,
                                             const unsigned short* __restrict__ kh,
                                             const unsigned short* __restrict__ vh,
                                             unsigned short* __restrict__ attn_out,
                                             int tile, int b, int h, int w, int quad,
                                             int lo, int lane,
                                             unsigned short* Kb, unsigned short* Vb) {
    const int G = tile * 128 + 16 * w;           // this wave's 16 q-rows
    const int a = (G + 15) >> 6;                 // last needed k-tile
    const int nkt = 2 * tile + 2;
    const int tq = G + lo;

    short8 qf[4];
    #pragma unroll
    for (int ks = 0; ks < 4; ks++)
        qf[ks] = *(const short8*)(qh + (size_t)(G + lo) * D_HEAD + ks * 32 + quad * 8);

    float m_i = -1e30f, l_i = 0.f;
    f32x4 o[8];
    #pragma unroll
    for (int dt = 0; dt < 8; dt++) o[dt] = (f32x4){0.f, 0.f, 0.f, 0.f};

    attn_stage(kh, vh, 0, Kb, Vb, w, lane);
    for (int kt = 0; kt < nkt; kt++) {
        const int cur = kt & 1;
        if (kt + 1 < nkt) {
            attn_stage(kh, vh, kt + 1, Kb + (cur ^ 1) * 8192, Vb + (cur ^ 1) * 8192, w, lane);
            __builtin_amdgcn_s_waitcnt(0x3F74);   // vmcnt(4): this tile's 4 loads done
        } else {
            __builtin_amdgcn_s_waitcnt(0x3F70);   // vmcnt(0)
        }
        __asm__ volatile("" ::: "memory");
        __builtin_amdgcn_s_barrier();
        __asm__ volatile("" ::: "memory");

        if (kt <= a) {                            // wave-uniform
            const unsigned short* Kc = Kb + cur * 8192;
            const unsigned short* Vc = Vb + cur * 8192;
            // QK: S^T[key][qrow] = K . Q^T
            f32x4 s[4];
            #pragma unroll
            for (int kg = 0; kg < 4; kg++) s[kg] = (f32x4){0.f, 0.f, 0.f, 0.f};
            #pragma unroll
            for (int kg = 0; kg < 4; kg++)
                #pragma unroll
                for (int ks = 0; ks < 4; ks++) {
                    int ch = (ks * 4 + quad) ^ lo;            // row&15 == lo
                    short8 kf = *(const short8*)(Kc + (kg * 16 + lo) * D_HEAD + ch * 8);
                    s[kg] = __builtin_amdgcn_mfma_f32_16x16x32_bf16(kf, qf[ks], s[kg], 0, 0, 0);
                }

            // online softmax (exp2 domain; scale folded into Q)
            const bool msk = (kt == a);
            float mx = -1e30f;
            #pragma unroll
            for (int kg = 0; kg < 4; kg++)
                #pragma unroll
                for (int r = 0; r < 4; r++) {
                    if (msk) {
                        int key = kt * 64 + kg * 16 + quad * 4 + r;
                        if (key > tq) s[kg][r] = -1e30f;
                    }
                    mx = fmaxf(mx, s[kg][r]);
                }
            mx = fmaxf(mx, __shfl_xor(mx, 16));
            mx = fmaxf(mx, __shfl_xor(mx, 32));
            float mnew = fmaxf(m_i, mx);
            float alpha = __builtin_amdgcn_exp2f(m_i - mnew);
            float sm = 0.f;
            short4v pp[4];
            #pragma unroll
            for (int kg = 0; kg < 4; kg++) {
                float p0 = __builtin_amdgcn_exp2f(s[kg][0] - mnew);
                float p1 = __builtin_amdgcn_exp2f(s[kg][1] - mnew);
                float p2 = __builtin_amdgcn_exp2f(s[kg][2] - mnew);
                float p3 = __builtin_amdgcn_exp2f(s[kg][3] - mnew);
                sm += (p0 + p1) + (p2 + p3);
                union { float f; unsigned u; } c0, c1, c2, c3;
                c0.f = p0; c1.f = p1; c2.f = p2; c3.f = p3;
                union { short4v s4; unsigned u[2]; } pu;
                pu.u[0] = (c0.u >> 16) | (c1.u & 0xFFFF0000u);   // truncated bf16
                pu.u[1] = (c2.u >> 16) | (c3.u & 0xFFFF0000u);
                pp[kg] = pu.s4;
            }
            sm += __shfl_xor(sm, 16);
            sm += __shfl_xor(sm, 32);
            l_i = l_i * alpha + sm;
            m_i = mnew;

            // PV: O^T[d][qrow] += V^T . P^T   (K=16 per key-group)
            #pragma unroll
            for (int dt = 0; dt < 8; dt++) {
                f32x4 oo = o[dt];
                #pragma unroll
                for (int r = 0; r < 4; r++) oo[r] *= alpha;
                #pragma unroll
                for (int kg = 0; kg < 4; kg++) {
                    int un = (kg * 4 + quad) ^ (lo & 14);     // vrow&14 == lo&14
                    short4v vv = *(const short4v*)(Vc + (dt * 16 + lo) * 64 + un * 4);
                    oo = pv_mfma(vv, pp[kg], oo);
                }
                o[dt] = oo;
            }
        }
        __asm__ volatile("" ::: "memory");
        __builtin_amdgcn_s_barrier();
        __asm__ volatile("" ::: "memory");
    }

    // epilogue: O^T C-layout lane(quad,lo): d = dt*16+quad*4+r, qrow = G+lo
    float inv_l = 1.f / l_i;
    size_t base = ((size_t)b * T_SEQ + G + lo) * C_DIM + h * D_HEAD + quad * 4;
    #pragma unroll
    for (int dt = 0; dt < 8; dt++) {
        uint2 u;
        u.x = (unsigned)f2bf(o[dt][0] * inv_l) | ((unsigned)f2bf(o[dt][1] * inv_l) << 16);
        u.y = (unsigned)f2bf(o[dt][2] * inv_l) | ((unsigned)f2bf(o[dt][3] * inv_l) << 16);
        *(uint2*)(attn_out + base + dt * 16) = u;
    }
}

__global__ __launch_bounds__(512, 4) void attn_kernel(const unsigned short* __restrict__ q,
                                                      const unsigned short* __restrict__ k,
                                                      const unsigned short* __restrict__ vt,
                                                      unsigned short* __restrict__ attn_out) {
    __shared__ unsigned short Kb[2 * 64 * 128];   // 32 KB
    __shared__ unsigned short Vb[2 * 128 * 64];   // 32 KB
    const int lane = threadIdx.x & 63;
    const int w = threadIdx.x >> 6;               // 0..7
    const int quad = lane >> 4, lo = lane & 15;
    const int bid = blockIdx.x;                   // 512 blocks = 2/CU
    const int head_lin = bid & 63;                // same head => same XCD (bid%8 const)
    const int pr = bid >> 6;                      // pair index 0..7
    const int b = head_lin >> 4, h = head_lin & 15;
    const unsigned short* qh = q + (size_t)head_lin * T_SEQ * D_HEAD;
    const unsigned short* kh = k + (size_t)head_lin * T_SEQ * D_HEAD;
    const unsigned short* vh = vt + (size_t)head_lin * D_HEAD * T_SEQ;

    attn_tile128(qh, kh, vh, attn_out, pr,      b, h, w, quad, lo, lane, Kb, Vb);  // light
    attn_tile128(qh, kh, vh, attn_out, 15 - pr, b, h, w, quad, lo, lane, Kb, Vb);  // heavy
}

// ---------------- launch -----------------------------------------------------
extern "C" void kernel_launch(void* const* d_in, const int* in_sizes, int n_in,
                              void* d_out, int out_size, void* d_ws, size_t ws_size,
                              hipStream_t stream) {
    const float* x    = (const float*)d_in[0];
    const float* ln_g = (const float*)d_in[1];
    const float* ln_b = (const float*)d_in[2];
    const float* Wq   = (const float*)d_in[3];
    const float* bq   = (const float*)d_in[4];
    const float* Wk   = (const float*)d_in[5];
    const float* bk   = (const float*)d_in[6];
    const float* Wv   = (const float*)d_in[7];
    const float* bv   = (const float*)d_in[8];
    const float* Wo   = (const float*)d_in[9];
    const float* bo   = (const float*)d_in[10];
    float* out = (float*)d_out;

    char* ws = (char*)d_ws;
    const size_t SZ = (size_t)M_ROWS * C_DIM * 2;        // 33,554,432 bytes
    unsigned short* nx  = (unsigned short*)(ws);
    unsigned short* wt  = (unsigned short*)(ws + SZ);    // 4 x 2048 x 2048 bf16
    unsigned short* qb  = (unsigned short*)(ws + 2 * SZ);
    unsigned short* kb  = (unsigned short*)(ws + 3 * SZ);
    unsigned short* vtb = (unsigned short*)(ws + 4 * SZ);
    unsigned short* at  = (unsigned short*)(ws + 5 * SZ);

    wcast_kernel<<<dim3(64, 64, 4), dim3(32, 8), 0, stream>>>(Wq, Wk, Wv, Wo, wt);
    ln_kernel<<<M_ROWS, 256, 0, stream>>>(x, ln_g, ln_b, nx);
    gemm_qkv<<<dim3(48, 64), 256, 0, stream>>>(nx, wt, bq, bk, bv, qb, kb, vtb);
    rope_kernel<<<dim3((B_NUM * H_NUM * T_SEQ * 64) / 256, 2), 256, 0, stream>>>(qb, kb);
    attn_kernel<<<512, 512, 0, stream>>>(qb, kb, vtb, at);
    gemm_out<<<dim3(16, 64), 256, 0, stream>>>(at, wt + (size_t)3 * C_DIM * C_DIM, bo, x, out);
}